// Round 2
// baseline (1121.289 us; speedup 1.0000x reference)
//
#include <hip/hip_runtime.h>
#include <cmath>
#include <cstdint>

#define NTOK   16384
#define DM     512
#define NEXP   8
#define LOG100 4.605170185988092f

typedef _Float16 half8  __attribute__((ext_vector_type(8)));
typedef float    floatx4 __attribute__((ext_vector_type(4)));

#define MFMA_F16(a, b, c) __builtin_amdgcn_mfma_f32_16x16x32_f16((a), (b), (c), 0, 0, 0)

// async global->LDS, 16B per lane. LDS dest wave-uniform base (HW adds lane*16);
// global side is per-lane addressed (gather OK).
__device__ __forceinline__ void gl_lds16(const void* g, void* l) {
    __builtin_amdgcn_global_load_lds(
        (const __attribute__((address_space(1))) void*)g,
        (__attribute__((address_space(3))) void*)l, 16, 0, 0);
}

// ---------------- ws layout ----------------
// ctrl (floats from ws base):
//   [0..31]   int cnt[2][2][8]   (layer, slot, expert)
//   [32..47]  float imp[2][8]
//   [48..49]  float vq[2]
//   [50..51]  float tsc[2]
//   [52..67]  float ia[2][8]
//   [128..8319]    float rmn[16*512]
//   [8320..73855]  float2 wts[2][16384]
// big = ws + 512KB:
//   w0hi 4MB | w0lo 4MB | w1h 4MB | h16 16MB | bkt(ushort) 2MB   => total ws 30.5MB
// xhi/xlo (16MB each) live in d_out's h1 region (dead until layer-1 GEMMs).

// =============================== prep ===============================
__global__ __launch_bounds__(256) void prep_kernel(
    const float* __restrict__ rm0, const float* __restrict__ rm1,
    const float* __restrict__ ca0, const float* __restrict__ ca1,
    const float* __restrict__ temp0, const float* __restrict__ temp1,
    float* __restrict__ ctrl, float* __restrict__ rmn)
{
    int tid = threadIdx.x, lane = tid & 63, w = tid >> 6;
    if (tid < 32) ((int*)ctrl)[tid] = 0;                       // cnt
    if (tid >= 32 && tid < 48) ctrl[tid] = 0.f;                // imp
    if (tid == 48 || tid == 49) ctrl[tid] = 0.f;               // vq
    if (tid == 50) ctrl[50] = expf(fminf(temp0[0], LOG100));
    if (tid == 51) ctrl[51] = expf(fminf(temp1[0], LOG100));
    if (tid >= 52 && tid < 68) {
        int i = tid - 52;
        ctrl[tid] = expf(fminf(i < 8 ? ca0[i] : ca1[i - 8], LOG100));
    }
    // normalize 16 memory rows (rm0: 0..7, rm1: 8..15); 4 waves, 4 rows/wave
    for (int r = w; r < 16; r += 4) {
        const float* src = (r < 8) ? (rm0 + r * DM) : (rm1 + (r - 8) * DM);
        float v[8]; float ss = 0.f;
        #pragma unroll
        for (int j = 0; j < 8; ++j) { v[j] = src[lane + 64 * j]; ss += v[j] * v[j]; }
        #pragma unroll
        for (int off = 32; off > 0; off >>= 1) ss += __shfl_xor(ss, off);
        float inv = 1.f / fmaxf(sqrtf(ss), 1e-12f);
        float* dst = rmn + r * DM;
        #pragma unroll
        for (int j = 0; j < 8; ++j) dst[lane + 64 * j] = v[j] * inv;
    }
}

// =============================== W conversion ===============================
__global__ __launch_bounds__(256) void conv_w_kernel(
    const float* __restrict__ W0, const float* __restrict__ W1,
    _Float16* __restrict__ w0hi, _Float16* __restrict__ w0lo, _Float16* __restrict__ w1h)
{
    for (int i = blockIdx.x * 256 + threadIdx.x; i < NEXP * DM * DM; i += 2048 * 256) {
        float a = W0[i];
        _Float16 h = (_Float16)a;
        w0hi[i] = h;
        w0lo[i] = (_Float16)(a - (float)h);
        w1h[i] = (_Float16)W1[i];
    }
}

// =============================== routing ===============================
// One wave per token, 8 tokens/wave sequentially, 32 tokens/block.
__global__ __launch_bounds__(256) void route_kernel(
    const float* __restrict__ src,      // [16384][512]
    const float* __restrict__ rmn,      // [8*512] normalized memory (this layer)
    int relu_in,
    _Float16* __restrict__ dst_hi,      // fp16 hi
    _Float16* __restrict__ dst_lo,      // fp16 lo or nullptr
    int* __restrict__ cnt,              // [2][8] this layer
    unsigned short* __restrict__ bkt,   // [2][8][16384] this layer
    float2* __restrict__ wts,           // [16384] this layer
    float* __restrict__ vq_acc,
    float* __restrict__ imp_acc)
{
    __shared__ float rmLds[NEXP * DM];
    __shared__ float red[9];
    int tid = threadIdx.x;
    for (int i = tid; i < NEXP * DM; i += 256) rmLds[i] = rmn[i];
    if (tid < 9) red[tid] = 0.f;
    __syncthreads();
    int lane = tid & 63, w = tid >> 6;

    for (int t = 0; t < 8; ++t) {
        int token = blockIdx.x * 32 + w * 8 + t;
        const float* row = src + (size_t)token * DM;
        float x[8]; float ss = 0.f;
        #pragma unroll
        for (int j = 0; j < 8; ++j) {
            float v = row[lane + 64 * j];
            if (relu_in) v = fmaxf(v, 0.f);
            x[j] = v; ss += v * v;
        }
        #pragma unroll
        for (int j = 0; j < 8; ++j) {
            _Float16 h = (_Float16)x[j];
            dst_hi[(size_t)token * DM + lane + 64 * j] = h;
            if (dst_lo) dst_lo[(size_t)token * DM + lane + 64 * j] = (_Float16)(x[j] - (float)h);
        }
        float d[8];
        #pragma unroll
        for (int e = 0; e < 8; ++e) {
            float a = 0.f;
            #pragma unroll
            for (int j = 0; j < 8; ++j) a += x[j] * rmLds[e * DM + lane + 64 * j];
            d[e] = a;
        }
        #pragma unroll
        for (int off = 32; off > 0; off >>= 1) {
            ss += __shfl_xor(ss, off);
            #pragma unroll
            for (int e = 0; e < 8; ++e) d[e] += __shfl_xor(d[e], off);
        }
        float inv = 1.f / fmaxf(sqrtf(ss), 1e-12f);
        // top-2 (ties -> lower index, matching lax.top_k)
        float best = -1e30f, second = -1e30f; int be = 0, se = 0;
        #pragma unroll
        for (int e = 0; e < 8; ++e) {
            float de = d[e] * inv;
            if (de > best)        { second = best; se = be; best = de; be = e; }
            else if (de > second) { second = de; se = e; }
        }
        float z = expf(second - best);
        float w0 = 1.f / (1.f + z), w1 = z / (1.f + z);
        if (lane == 0) {
            int p0 = atomicAdd(&cnt[be], 1);
            bkt[be * NTOK + p0] = (unsigned short)token;
            int p1 = atomicAdd(&cnt[8 + se], 1);
            bkt[(8 + se) * NTOK + p1] = (unsigned short)token;
            wts[token] = make_float2(w0, w1);
            atomicAdd(&red[8], -(w0 * best + w1 * second));
            atomicAdd(&red[be], w0);
            atomicAdd(&red[se], w1);
        }
    }
    __syncthreads();
    if (tid < 8) atomicAdd(&imp_acc[tid], red[tid]);
    if (tid == 8) atomicAdd(vq_acc, red[8]);
}

// =============================== grouped GEMM ===============================
// 128x128 tile, 4 waves (2x2 of 64x64), 16x16x32 f16 MFMA.
// LDS: [128 rows][64 halves], 8 chunks of 8 halves/row, XOR-swizzled p=c^(row&7)
// -> max 2-way bank aliasing (free) on ds_read_b128.
// SPLIT: chunks 0-3 = hi(k0..31), 4-7 = lo(k0..31), KSTEP=32. Plain: 64 k's.
template <bool SPLIT>
__global__ __launch_bounds__(256) void gemm_kernel(
    const _Float16* __restrict__ Ahi, const _Float16* __restrict__ Alo,
    const _Float16* __restrict__ Whi, const _Float16* __restrict__ Wlo,
    const float* __restrict__ bias,   // [8][512]
    const float* __restrict__ iav,    // [8]
    const float* __restrict__ tscp,
    const int* __restrict__ cnt,      // [8] this layer+slot
    const unsigned short* __restrict__ bkt, // [8][16384]
    const float2* __restrict__ wts,   // [16384]
    int slot, int accum,
    float* __restrict__ outp)
{
    __shared__ __align__(16) _Float16 lds[2 * 128 * 64];
    __shared__ int tokLds[128];
    _Float16* tA = lds;
    _Float16* tB = lds + 128 * 64;

    int e = blockIdx.x >> 7, mt = blockIdx.x & 127;
    int M = cnt[e];
    int m0 = mt << 7;
    if (m0 >= M) return;
    int n0 = blockIdx.y << 7;
    int valid = min(128, M - m0);
    int tid = threadIdx.x, lane = tid & 63, w = tid >> 6;
    if (tid < 128) tokLds[tid] = bkt[e * NTOK + m0 + min(tid, valid - 1)];
    __syncthreads();

    floatx4 acc[4][4];
    #pragma unroll
    for (int mi = 0; mi < 4; ++mi)
        #pragma unroll
        for (int ni = 0; ni < 4; ++ni) acc[mi][ni] = (floatx4){0.f, 0.f, 0.f, 0.f};

    const _Float16* WbH = Whi + ((size_t)e * DM + n0) * DM;
    const _Float16* WbL = SPLIT ? (Wlo + ((size_t)e * DM + n0) * DM) : nullptr;

    int subRow = lane >> 3, p = lane & 7;
    int cSt = p ^ (subRow & 7);
    int wm = w >> 1, wn = w & 1;
    int r0 = wm * 64, c0 = wn * 64;
    int q = lane >> 4, l15 = lane & 15;

    constexpr int KIT = SPLIT ? 16 : 8;
    constexpr int KSTEP = SPLIT ? 32 : 64;

    for (int kb = 0; kb < KIT; ++kb) {
        int k0 = kb * KSTEP;
        #pragma unroll
        for (int j = w; j < 16; j += 4) {
            int row = j * 8 + subRow;
            int tok = tokLds[row];
            const _Float16* g;
            if constexpr (SPLIT)
                g = (cSt < 4) ? (Ahi + (size_t)tok * DM + k0 + cSt * 8)
                              : (Alo + (size_t)tok * DM + k0 + (cSt - 4) * 8);
            else
                g = Ahi + (size_t)tok * DM + k0 + cSt * 8;
            gl_lds16(g, (void*)(tA + j * 512));
        }
        #pragma unroll
        for (int j = w; j < 16; j += 4) {
            int row = j * 8 + subRow;
            const _Float16* g;
            if constexpr (SPLIT)
                g = (cSt < 4) ? (WbH + (size_t)row * DM + k0 + cSt * 8)
                              : (WbL + (size_t)row * DM + k0 + (cSt - 4) * 8);
            else
                g = WbH + (size_t)row * DM + k0 + cSt * 8;
            gl_lds16(g, (void*)(tB + j * 512));
        }
        __syncthreads();

        if constexpr (SPLIT) {
            half8 ah[4], al[4];
            #pragma unroll
            for (int mi = 0; mi < 4; ++mi) {
                int r = r0 + mi * 16 + l15;
                int ph = q ^ (r & 7), pl = (q + 4) ^ (r & 7);
                ah[mi] = *(const half8*)(tA + r * 64 + ph * 8);
                al[mi] = *(const half8*)(tA + r * 64 + pl * 8);
            }
            #pragma unroll
            for (int ni = 0; ni < 4; ++ni) {
                int r = c0 + ni * 16 + l15;
                int ph = q ^ (r & 7), pl = (q + 4) ^ (r & 7);
                half8 bh = *(const half8*)(tB + r * 64 + ph * 8);
                half8 bl = *(const half8*)(tB + r * 64 + pl * 8);
                #pragma unroll
                for (int mi = 0; mi < 4; ++mi) acc[mi][ni] = MFMA_F16(ah[mi], bh, acc[mi][ni]);
                #pragma unroll
                for (int mi = 0; mi < 4; ++mi) acc[mi][ni] = MFMA_F16(ah[mi], bl, acc[mi][ni]);
                #pragma unroll
                for (int mi = 0; mi < 4; ++mi) acc[mi][ni] = MFMA_F16(al[mi], bh, acc[mi][ni]);
            }
        } else {
            #pragma unroll
            for (int ks = 0; ks < 2; ++ks) {
                half8 a[4];
                #pragma unroll
                for (int mi = 0; mi < 4; ++mi) {
                    int r = r0 + mi * 16 + l15;
                    int pc = (ks * 4 + q) ^ (r & 7);
                    a[mi] = *(const half8*)(tA + r * 64 + pc * 8);
                }
                #pragma unroll
                for (int ni = 0; ni < 4; ++ni) {
                    int r = c0 + ni * 16 + l15;
                    int pc = (ks * 4 + q) ^ (r & 7);
                    half8 b = *(const half8*)(tB + r * 64 + pc * 8);
                    #pragma unroll
                    for (int mi = 0; mi < 4; ++mi) acc[mi][ni] = MFMA_F16(a[mi], b, acc[mi][ni]);
                }
            }
        }
        __syncthreads();
    }

    // epilogue: C/D layout col=lane&15, row=(lane>>4)*4+reg
    float t = *tscp, iae = iav[e];
    float bv[4];
    #pragma unroll
    for (int ni = 0; ni < 4; ++ni) bv[ni] = bias[e * DM + n0 + c0 + ni * 16 + l15];
    #pragma unroll
    for (int mi = 0; mi < 4; ++mi) {
        int liBase = r0 + mi * 16 + q * 4;
        #pragma unroll
        for (int reg = 0; reg < 4; ++reg) {
            int li = liBase + reg;
            if (li < valid) {
                int tok = tokLds[li];
                float2 wp = wts[tok];
                float wgt = slot ? wp.y : wp.x;
                float sg = t * wgt * iae, sb = t * wgt;
                float* orow = outp + (size_t)tok * DM + n0;
                #pragma unroll
                for (int ni = 0; ni < 4; ++ni) {
                    float v = acc[mi][ni][reg] * sg + bv[ni] * sb;
                    int c = c0 + ni * 16 + l15;
                    if (accum) orow[c] += v; else orow[c] = v;
                }
            }
        }
    }
}

// =============================== finalize aux ===============================
__global__ void finalize_kernel(const float* __restrict__ ctrl, float* __restrict__ outp)
{
    if (threadIdx.x == 0) {
        float aux = 0.f;
        for (int l = 0; l < 2; ++l) {
            float vq = ctrl[48 + l] / (float)NTOK;
            float mean = 0.f;
            for (int e = 0; e < 8; ++e) mean += ctrl[32 + l * 8 + e];
            mean *= 0.125f;
            float s = 0.f;
            for (int e = 0; e < 8; ++e) {
                float d = ctrl[32 + l * 8 + e] - mean;
                s += d * d;
            }
            float var = s / 7.f;                       // ddof=1
            float lb = var / (mean * mean + 1e-10f);
            aux += 0.05f * vq + 0.01f * lb;
        }
        *outp = aux;
    }
}

// =============================== launch ===============================
extern "C" void kernel_launch(void* const* d_in, const int* in_sizes, int n_in,
                              void* d_out, int out_size, void* d_ws, size_t ws_size,
                              hipStream_t stream) {
    const float* x     = (const float*)d_in[0];
    const float* rm0   = (const float*)d_in[1];
    const float* W0    = (const float*)d_in[2];
    const float* b0    = (const float*)d_in[3];
    const float* temp0 = (const float*)d_in[4];
    const float* ca0   = (const float*)d_in[5];
    const float* rm1   = (const float*)d_in[6];
    const float* W1    = (const float*)d_in[7];
    const float* b1    = (const float*)d_in[8];
    const float* temp1 = (const float*)d_in[9];
    const float* ca1   = (const float*)d_in[10];
    float* out = (float*)d_out;

    char* ws = (char*)d_ws;
    float* ctrl = (float*)ws;
    int*   cnt  = (int*)ctrl;                 // [2][2][8]
    float* imp  = ctrl + 32;                  // [2][8]
    float* vq   = ctrl + 48;                  // [2]
    float* tsc  = ctrl + 50;                  // [2]
    float* ia   = ctrl + 52;                  // [2][8]
    float* rmn  = ctrl + 128;                 // [16][512]
    float2* wts = (float2*)(ctrl + 8320);     // [2][16384]

    char* big = ws + (512 << 10);             // 512KB
    _Float16*       w0hi = (_Float16*)(big);                               // 4MB
    _Float16*       w0lo = (_Float16*)(big + (size_t)4  * 1024 * 1024);    // 4MB
    _Float16*       w1h  = (_Float16*)(big + (size_t)8  * 1024 * 1024);    // 4MB
    _Float16*       h16  = (_Float16*)(big + (size_t)12 * 1024 * 1024);    // 16MB
    unsigned short* bkt  = (unsigned short*)(big + (size_t)28 * 1024 * 1024); // 2MB
    // total ws use: 30.5MB

    // xhi/xlo live in d_out's h1 region (32MB), dead until layer-1 GEMMs
    _Float16* xhi = (_Float16*)(out + (size_t)NTOK * DM);
    _Float16* xlo = xhi + (size_t)NTOK * DM;

    prep_kernel<<<1, 256, 0, stream>>>(rm0, rm1, ca0, ca1, temp0, temp1, ctrl, rmn);
    conv_w_kernel<<<2048, 256, 0, stream>>>(W0, W1, w0hi, w0lo, w1h);

    // layer 0
    route_kernel<<<512, 256, 0, stream>>>(x, rmn, 0, xhi, xlo,
        cnt, bkt, wts, vq, imp);
    gemm_kernel<true><<<dim3(1024, 4), 256, 0, stream>>>(xhi, xlo, w0hi, w0lo, b0, ia, tsc,
        cnt, bkt, wts, 0, 0, out);
    gemm_kernel<true><<<dim3(1024, 4), 256, 0, stream>>>(xhi, xlo, w0hi, w0lo, b0, ia, tsc,
        cnt + 8, bkt + 8 * NTOK, wts, 1, 1, out);

    // layer 1 (routes on h_emb in d_out; relu + h->fp16 fused in route)
    route_kernel<<<512, 256, 0, stream>>>(out, rmn + 4096, 1, h16, (_Float16*)nullptr,
        cnt + 16, bkt + 16 * NTOK, wts + NTOK, vq + 1, imp + 8);
    gemm_kernel<false><<<dim3(1024, 4), 256, 0, stream>>>(h16, (const _Float16*)nullptr, w1h,
        (const _Float16*)nullptr, b1, ia + 8, tsc + 1,
        cnt + 16, bkt + 16 * NTOK, wts + NTOK, 0, 0, out + (size_t)NTOK * DM);
    gemm_kernel<false><<<dim3(1024, 4), 256, 0, stream>>>(h16, (const _Float16*)nullptr, w1h,
        (const _Float16*)nullptr, b1, ia + 8, tsc + 1,
        cnt + 24, bkt + 24 * NTOK, wts + NTOK, 1, 1, out + (size_t)NTOK * DM);

    finalize_kernel<<<1, 64, 0, stream>>>(ctrl, out + (size_t)2 * NTOK * DM);
}

// Round 3
// 492.638 us; speedup vs baseline: 2.2761x; 2.2761x over previous
//
#include <hip/hip_runtime.h>
#include <cmath>
#include <cstdint>

#define NTOK   16384
#define DM     512
#define NEXP   8
#define LOG100 4.605170185988092f

typedef _Float16 half8  __attribute__((ext_vector_type(8)));
typedef _Float16 half4  __attribute__((ext_vector_type(4)));
typedef float    floatx4 __attribute__((ext_vector_type(4)));

#define MFMA_F16(a, b, c) __builtin_amdgcn_mfma_f32_16x16x32_f16((a), (b), (c), 0, 0, 0)

// async global->LDS, 16B per lane. LDS dest wave-uniform base (HW adds lane*16).
__device__ __forceinline__ void gl_lds16(const void* g, void* l) {
    __builtin_amdgcn_global_load_lds(
        (const __attribute__((address_space(1))) void*)g,
        (__attribute__((address_space(3))) void*)l, 16, 0, 0);
}

// ---------------- ws layout ----------------
// ctrl floats @ws: [0..31] int cnt[2][2][8] | [32..47] imp[2][8] | [48..49] vq[2]
//                  [50..51] tsc[2] | [52..67] ia[2][8] | [128..8319] rmn[16*512]
// @ws+64KB:  float2 wts[2][16384]  (256KB)
// @ws+384KB: float2 bs[2][16384]   (256KB, (best,second) dists)
// @ws+704KB: uchar key[2][2][16384] (64KB, [layer][slot][tok])
// @ws+1MB:   w0hi 4MB | w0lo 4MB | w1h 4MB | h16 16MB | bkt(ushort) 2MB  => 31MB total
// xhi/xlo (16MB each) live in d_out's h1 region (dead until layer-1 GEMMs).

// =============================== prep ===============================
__global__ __launch_bounds__(256) void prep_kernel(
    const float* __restrict__ rm0, const float* __restrict__ rm1,
    const float* __restrict__ ca0, const float* __restrict__ ca1,
    const float* __restrict__ temp0, const float* __restrict__ temp1,
    float* __restrict__ ctrl, float* __restrict__ rmn)
{
    int tid = threadIdx.x, lane = tid & 63, w = tid >> 6;
    if (tid < 32) ((int*)ctrl)[tid] = 0;                       // cnt
    if (tid >= 32 && tid < 48) ctrl[tid] = 0.f;                // imp
    if (tid == 48 || tid == 49) ctrl[tid] = 0.f;               // vq
    if (tid == 50) ctrl[50] = expf(fminf(temp0[0], LOG100));
    if (tid == 51) ctrl[51] = expf(fminf(temp1[0], LOG100));
    if (tid >= 52 && tid < 68) {
        int i = tid - 52;
        ctrl[tid] = expf(fminf(i < 8 ? ca0[i] : ca1[i - 8], LOG100));
    }
    for (int r = w; r < 16; r += 4) {
        const float* src = (r < 8) ? (rm0 + r * DM) : (rm1 + (r - 8) * DM);
        float v[8]; float ss = 0.f;
        #pragma unroll
        for (int j = 0; j < 8; ++j) { v[j] = src[lane + 64 * j]; ss += v[j] * v[j]; }
        #pragma unroll
        for (int off = 32; off > 0; off >>= 1) ss += __shfl_xor(ss, off);
        float inv = 1.f / fmaxf(sqrtf(ss), 1e-12f);
        float* dst = rmn + r * DM;
        #pragma unroll
        for (int j = 0; j < 8; ++j) dst[lane + 64 * j] = v[j] * inv;
    }
}

// =============================== W conversion (float4-vectorized) ===============================
__global__ __launch_bounds__(256) void conv_w_kernel(
    const float4* __restrict__ W0, const float4* __restrict__ W1,
    half4* __restrict__ w0hi, half4* __restrict__ w0lo, half4* __restrict__ w1h)
{
    int i = blockIdx.x * 256 + threadIdx.x;          // 2048*256 == 2M/4 exactly
    float4 a = W0[i], b = W1[i];
    const float* ap = (const float*)&a;
    const float* bp = (const float*)&b;
    half4 hi, lo, h1;
    #pragma unroll
    for (int j = 0; j < 4; ++j) {
        _Float16 h = (_Float16)ap[j];
        hi[j] = h;
        lo[j] = (_Float16)(ap[j] - (float)h);
        h1[j] = (_Float16)bp[j];
    }
    w0hi[i] = hi; w0lo[i] = lo; w1h[i] = h1;
}

// =============================== routing (1 token / wave, no atomics) ===============================
__global__ __launch_bounds__(256) void route_kernel(
    const float* __restrict__ src,      // [16384][512]
    const float* __restrict__ rmn,      // [8*512] normalized memory (this layer)
    int relu_in,
    _Float16* __restrict__ dst_hi,      // fp16 hi
    _Float16* __restrict__ dst_lo,      // fp16 lo or nullptr
    unsigned char* __restrict__ key,    // [2][16384] this layer (slot-major)
    float2* __restrict__ wts,           // [16384] this layer
    float2* __restrict__ bs)            // [16384] this layer (best,second)
{
    __shared__ float rmLds[NEXP * DM];
    int tid = threadIdx.x;
    for (int i = tid; i < NEXP * DM; i += 256) rmLds[i] = rmn[i];
    __syncthreads();
    int lane = tid & 63, w = tid >> 6;
    int token = blockIdx.x * 4 + w;

    const float* row = src + (size_t)token * DM;
    float x[8]; float ss = 0.f;
    #pragma unroll
    for (int j = 0; j < 8; ++j) {
        float v = row[lane + 64 * j];
        if (relu_in) v = fmaxf(v, 0.f);
        x[j] = v; ss += v * v;
    }
    #pragma unroll
    for (int j = 0; j < 8; ++j) {
        _Float16 h = (_Float16)x[j];
        dst_hi[(size_t)token * DM + lane + 64 * j] = h;
        if (dst_lo) dst_lo[(size_t)token * DM + lane + 64 * j] = (_Float16)(x[j] - (float)h);
    }
    float d[8];
    #pragma unroll
    for (int e = 0; e < 8; ++e) {
        float a = 0.f;
        #pragma unroll
        for (int j = 0; j < 8; ++j) a += x[j] * rmLds[e * DM + lane + 64 * j];
        d[e] = a;
    }
    #pragma unroll
    for (int off = 32; off > 0; off >>= 1) {
        ss += __shfl_xor(ss, off);
        #pragma unroll
        for (int e = 0; e < 8; ++e) d[e] += __shfl_xor(d[e], off);
    }
    float inv = 1.f / fmaxf(sqrtf(ss), 1e-12f);
    // top-2 (ties -> lower index, matching lax.top_k)
    float best = -1e30f, second = -1e30f; int be = 0, se = 0;
    #pragma unroll
    for (int e = 0; e < 8; ++e) {
        float de = d[e] * inv;
        if (de > best)        { second = best; se = be; best = de; be = e; }
        else if (de > second) { second = de; se = e; }
    }
    float z = expf(second - best);
    float w0 = 1.f / (1.f + z), w1 = z / (1.f + z);
    if (lane == 0) {
        key[token] = (unsigned char)be;
        key[NTOK + token] = (unsigned char)se;
        wts[token] = make_float2(w0, w1);
        bs[token] = make_float2(best, second);
    }
}

// =============================== bucket compaction ===============================
// 16 blocks: block = slot*8 + e. Deterministic ascending-token compaction via
// ballot/popcount; writes exact count, bucket list, imp (2 atomics/e), vq (16 atomics).
__global__ __launch_bounds__(256) void compact_kernel(
    const unsigned char* __restrict__ key,  // [2][16384] this layer
    const float2* __restrict__ wts,         // [16384]
    const float2* __restrict__ bs,          // [16384]
    int* __restrict__ cnt,                  // [2][8] this layer
    unsigned short* __restrict__ bkt,       // [2][8][16384] this layer
    float* __restrict__ imp,                // [8] this layer
    float* __restrict__ vq_acc)             // &vq[layer]
{
    int slot = blockIdx.x >> 3, e = blockIdx.x & 7;
    const unsigned char* k = key + slot * NTOK;
    unsigned short* ob = bkt + (size_t)(slot * 8 + e) * NTOK;
    __shared__ int wc[2][4];
    int tid = threadIdx.x, lane = tid & 63, w = tid >> 6;
    int base = 0;
    float wsum = 0.f, vqs = 0.f;
    for (int c = 0; c < 64; ++c) {
        int tok = c * 256 + tid;
        bool m = (k[tok] == (unsigned char)e);
        unsigned long long mask = __ballot(m);
        int p = c & 1;
        if (lane == 0) wc[p][w] = __popcll(mask);
        __syncthreads();
        int off = base;
        for (int i = 0; i < w; ++i) off += wc[p][i];
        if (m) {
            int pre = __popcll(mask & ((1ull << lane) - 1ull));
            ob[off + pre] = (unsigned short)tok;
            float2 wp = wts[tok]; float2 b2 = bs[tok];
            float wv = slot ? wp.y : wp.x;
            wsum += wv;
            vqs  += wv * (slot ? b2.y : b2.x);
        }
        base += wc[p][0] + wc[p][1] + wc[p][2] + wc[p][3];
    }
    // block reduce wsum/vqs
    #pragma unroll
    for (int off = 32; off > 0; off >>= 1) {
        wsum += __shfl_xor(wsum, off);
        vqs  += __shfl_xor(vqs, off);
    }
    __shared__ float rw[4], rv[4];
    if (lane == 0) { rw[w] = wsum; rv[w] = vqs; }
    __syncthreads();
    if (tid == 0) {
        cnt[slot * 8 + e] = base;
        float W = rw[0] + rw[1] + rw[2] + rw[3];
        float V = rv[0] + rv[1] + rv[2] + rv[3];
        atomicAdd(&imp[e], W);
        atomicAdd(vq_acc, -V);
    }
}

// =============================== grouped GEMM ===============================
// 128x128 tile, 4 waves (2x2 of 64x64), 16x16x32 f16 MFMA.
// LDS: [128 rows][64 halves], 8 chunks of 8 halves/row, XOR-swizzled p=c^(row&7).
// SPLIT: chunks 0-3 = hi(k0..31), 4-7 = lo(k0..31), KSTEP=32. Plain: 64 k's.
template <bool SPLIT>
__global__ __launch_bounds__(256) void gemm_kernel(
    const _Float16* __restrict__ Ahi, const _Float16* __restrict__ Alo,
    const _Float16* __restrict__ Whi, const _Float16* __restrict__ Wlo,
    const float* __restrict__ bias,   // [8][512]
    const float* __restrict__ iav,    // [8]
    const float* __restrict__ tscp,
    const int* __restrict__ cnt,      // [8] this layer+slot
    const unsigned short* __restrict__ bkt, // [8][16384]
    const float2* __restrict__ wts,   // [16384]
    int slot, int accum,
    float* __restrict__ outp)
{
    __shared__ __align__(16) _Float16 lds[2 * 128 * 64];
    __shared__ int tokLds[128];
    _Float16* tA = lds;
    _Float16* tB = lds + 128 * 64;

    int e = blockIdx.x >> 7, mt = blockIdx.x & 127;
    int M = cnt[e];
    int m0 = mt << 7;
    if (m0 >= M) return;
    int n0 = blockIdx.y << 7;
    int valid = min(128, M - m0);
    int tid = threadIdx.x, lane = tid & 63, w = tid >> 6;
    if (tid < 128) tokLds[tid] = bkt[e * NTOK + m0 + min(tid, valid - 1)];
    __syncthreads();

    floatx4 acc[4][4];
    #pragma unroll
    for (int mi = 0; mi < 4; ++mi)
        #pragma unroll
        for (int ni = 0; ni < 4; ++ni) acc[mi][ni] = (floatx4){0.f, 0.f, 0.f, 0.f};

    const _Float16* WbH = Whi + ((size_t)e * DM + n0) * DM;
    const _Float16* WbL = SPLIT ? (Wlo + ((size_t)e * DM + n0) * DM) : nullptr;

    int subRow = lane >> 3, p = lane & 7;
    int cSt = p ^ (subRow & 7);
    int wm = w >> 1, wn = w & 1;
    int r0 = wm * 64, c0 = wn * 64;
    int q = lane >> 4, l15 = lane & 15;

    constexpr int KIT = SPLIT ? 16 : 8;
    constexpr int KSTEP = SPLIT ? 32 : 64;

    for (int kb = 0; kb < KIT; ++kb) {
        int k0 = kb * KSTEP;
        #pragma unroll
        for (int j = w; j < 16; j += 4) {
            int row = j * 8 + subRow;
            int tok = tokLds[row];
            const _Float16* g;
            if constexpr (SPLIT)
                g = (cSt < 4) ? (Ahi + (size_t)tok * DM + k0 + cSt * 8)
                              : (Alo + (size_t)tok * DM + k0 + (cSt - 4) * 8);
            else
                g = Ahi + (size_t)tok * DM + k0 + cSt * 8;
            gl_lds16(g, (void*)(tA + j * 512));
        }
        #pragma unroll
        for (int j = w; j < 16; j += 4) {
            int row = j * 8 + subRow;
            const _Float16* g;
            if constexpr (SPLIT)
                g = (cSt < 4) ? (WbH + (size_t)row * DM + k0 + cSt * 8)
                              : (WbL + (size_t)row * DM + k0 + (cSt - 4) * 8);
            else
                g = WbH + (size_t)row * DM + k0 + cSt * 8;
            gl_lds16(g, (void*)(tB + j * 512));
        }
        __syncthreads();

        if constexpr (SPLIT) {
            half8 ah[4], al[4];
            #pragma unroll
            for (int mi = 0; mi < 4; ++mi) {
                int r = r0 + mi * 16 + l15;
                int ph = q ^ (r & 7), pl = (q + 4) ^ (r & 7);
                ah[mi] = *(const half8*)(tA + r * 64 + ph * 8);
                al[mi] = *(const half8*)(tA + r * 64 + pl * 8);
            }
            #pragma unroll
            for (int ni = 0; ni < 4; ++ni) {
                int r = c0 + ni * 16 + l15;
                int ph = q ^ (r & 7), pl = (q + 4) ^ (r & 7);
                half8 bh = *(const half8*)(tB + r * 64 + ph * 8);
                half8 bl = *(const half8*)(tB + r * 64 + pl * 8);
                #pragma unroll
                for (int mi = 0; mi < 4; ++mi) acc[mi][ni] = MFMA_F16(ah[mi], bh, acc[mi][ni]);
                #pragma unroll
                for (int mi = 0; mi < 4; ++mi) acc[mi][ni] = MFMA_F16(ah[mi], bl, acc[mi][ni]);
                #pragma unroll
                for (int mi = 0; mi < 4; ++mi) acc[mi][ni] = MFMA_F16(al[mi], bh, acc[mi][ni]);
            }
        } else {
            #pragma unroll
            for (int ks = 0; ks < 2; ++ks) {
                half8 a[4];
                #pragma unroll
                for (int mi = 0; mi < 4; ++mi) {
                    int r = r0 + mi * 16 + l15;
                    int pc = (ks * 4 + q) ^ (r & 7);
                    a[mi] = *(const half8*)(tA + r * 64 + pc * 8);
                }
                #pragma unroll
                for (int ni = 0; ni < 4; ++ni) {
                    int r = c0 + ni * 16 + l15;
                    int pc = (ks * 4 + q) ^ (r & 7);
                    half8 b = *(const half8*)(tB + r * 64 + pc * 8);
                    #pragma unroll
                    for (int mi = 0; mi < 4; ++mi) acc[mi][ni] = MFMA_F16(a[mi], b, acc[mi][ni]);
                }
            }
        }
        __syncthreads();
    }

    // epilogue: C/D layout col=lane&15, row=(lane>>4)*4+reg
    float t = *tscp, iae = iav[e];
    float bv[4];
    #pragma unroll
    for (int ni = 0; ni < 4; ++ni) bv[ni] = bias[e * DM + n0 + c0 + ni * 16 + l15];
    #pragma unroll
    for (int mi = 0; mi < 4; ++mi) {
        int liBase = r0 + mi * 16 + q * 4;
        #pragma unroll
        for (int reg = 0; reg < 4; ++reg) {
            int li = liBase + reg;
            if (li < valid) {
                int tok = tokLds[li];
                float2 wp = wts[tok];
                float wgt = slot ? wp.y : wp.x;
                float sg = t * wgt * iae, sb = t * wgt;
                float* orow = outp + (size_t)tok * DM + n0;
                #pragma unroll
                for (int ni = 0; ni < 4; ++ni) {
                    float v = acc[mi][ni][reg] * sg + bv[ni] * sb;
                    int c = c0 + ni * 16 + l15;
                    if (accum) orow[c] += v; else orow[c] = v;
                }
            }
        }
    }
}

// =============================== finalize aux ===============================
__global__ void finalize_kernel(const float* __restrict__ ctrl, float* __restrict__ outp)
{
    if (threadIdx.x == 0) {
        float aux = 0.f;
        for (int l = 0; l < 2; ++l) {
            float vq = ctrl[48 + l] / (float)NTOK;
            float mean = 0.f;
            for (int e = 0; e < 8; ++e) mean += ctrl[32 + l * 8 + e];
            mean *= 0.125f;
            float s = 0.f;
            for (int e = 0; e < 8; ++e) {
                float d = ctrl[32 + l * 8 + e] - mean;
                s += d * d;
            }
            float var = s / 7.f;                       // ddof=1
            float lb = var / (mean * mean + 1e-10f);
            aux += 0.05f * vq + 0.01f * lb;
        }
        *outp = aux;
    }
}

// =============================== launch ===============================
extern "C" void kernel_launch(void* const* d_in, const int* in_sizes, int n_in,
                              void* d_out, int out_size, void* d_ws, size_t ws_size,
                              hipStream_t stream) {
    const float* x     = (const float*)d_in[0];
    const float* rm0   = (const float*)d_in[1];
    const float* W0    = (const float*)d_in[2];
    const float* b0    = (const float*)d_in[3];
    const float* temp0 = (const float*)d_in[4];
    const float* ca0   = (const float*)d_in[5];
    const float* rm1   = (const float*)d_in[6];
    const float* W1    = (const float*)d_in[7];
    const float* b1    = (const float*)d_in[8];
    const float* temp1 = (const float*)d_in[9];
    const float* ca1   = (const float*)d_in[10];
    float* out = (float*)d_out;

    char* ws = (char*)d_ws;
    float* ctrl = (float*)ws;
    int*   cnt  = (int*)ctrl;                 // [2][2][8]
    float* imp  = ctrl + 32;                  // [2][8]
    float* vq   = ctrl + 48;                  // [2]
    float* tsc  = ctrl + 50;                  // [2]
    float* ia   = ctrl + 52;                  // [2][8]
    float* rmn  = ctrl + 128;                 // [16][512]
    float2*        wts = (float2*)(ws + (size_t)64  * 1024);  // [2][16384]
    float2*        bs  = (float2*)(ws + (size_t)384 * 1024);  // [2][16384]
    unsigned char* key = (unsigned char*)(ws + (size_t)704 * 1024); // [2][2][16384]

    char* big = ws + (1 << 20);
    half4*          w0hi4 = (half4*)(big);                                 // 4MB
    half4*          w0lo4 = (half4*)(big + (size_t)4  * 1024 * 1024);      // 4MB
    half4*          w1h4  = (half4*)(big + (size_t)8  * 1024 * 1024);      // 4MB
    _Float16*       w0hi  = (_Float16*)w0hi4;
    _Float16*       w0lo  = (_Float16*)w0lo4;
    _Float16*       w1h   = (_Float16*)w1h4;
    _Float16*       h16   = (_Float16*)(big + (size_t)12 * 1024 * 1024);   // 16MB
    unsigned short* bkt   = (unsigned short*)(big + (size_t)28 * 1024 * 1024); // 2MB
    // total ws use: 31MB

    // xhi/xlo live in d_out's h1 region (32MB), dead until layer-1 GEMMs
    _Float16* xhi = (_Float16*)(out + (size_t)NTOK * DM);
    _Float16* xlo = xhi + (size_t)NTOK * DM;

    prep_kernel<<<1, 256, 0, stream>>>(rm0, rm1, ca0, ca1, temp0, temp1, ctrl, rmn);
    conv_w_kernel<<<2048, 256, 0, stream>>>((const float4*)W0, (const float4*)W1,
                                            w0hi4, w0lo4, w1h4);

    // layer 0
    route_kernel<<<4096, 256, 0, stream>>>(x, rmn, 0, xhi, xlo,
        key, wts, bs);
    compact_kernel<<<16, 256, 0, stream>>>(key, wts, bs, cnt, bkt, imp, vq);
    gemm_kernel<true><<<dim3(1024, 4), 256, 0, stream>>>(xhi, xlo, w0hi, w0lo, b0, ia, tsc,
        cnt, bkt, wts, 0, 0, out);
    gemm_kernel<true><<<dim3(1024, 4), 256, 0, stream>>>(xhi, xlo, w0hi, w0lo, b0, ia, tsc,
        cnt + 8, bkt + 8 * NTOK, wts, 1, 1, out);

    // layer 1 (routes on h_emb in d_out; relu + h->fp16 fused in route)
    route_kernel<<<4096, 256, 0, stream>>>(out, rmn + 4096, 1, h16, (_Float16*)nullptr,
        key + 2 * NTOK, wts + NTOK, bs + NTOK);
    compact_kernel<<<16, 256, 0, stream>>>(key + 2 * NTOK, wts + NTOK, bs + NTOK,
        cnt + 16, bkt + 16 * NTOK, imp + 8, vq + 1);
    gemm_kernel<false><<<dim3(1024, 4), 256, 0, stream>>>(h16, (const _Float16*)nullptr, w1h,
        (const _Float16*)nullptr, b1, ia + 8, tsc + 1,
        cnt + 16, bkt + 16 * NTOK, wts + NTOK, 0, 0, out + (size_t)NTOK * DM);
    gemm_kernel<false><<<dim3(1024, 4), 256, 0, stream>>>(h16, (const _Float16*)nullptr, w1h,
        (const _Float16*)nullptr, b1, ia + 8, tsc + 1,
        cnt + 24, bkt + 24 * NTOK, wts + NTOK, 1, 1, out + (size_t)NTOK * DM);

    finalize_kernel<<<1, 64, 0, stream>>>(ctrl, out + (size_t)2 * NTOK * DM);
}